// Round 1
// baseline (484.695 us; speedup 1.0000x reference)
//
#include <hip/hip_runtime.h>
#include <math.h>

// Problem constants (fixed by setup_inputs)
#define BB 512
#define CC 480          // C1*C2 = 16*30
#define HW 225          // 15*15
#define NCH (BB*CC)     // 245760 channels

// Kernel 1: per-channel full mean and center-3x3 (ring) mean.
// One 64-lane wave per channel; 4 waves per 256-thread block.
__global__ __launch_bounds__(256) void means_kernel(
    const float* __restrict__ x, float* __restrict__ M, float* __restrict__ R)
{
    const int wave = threadIdx.x >> 6;
    const int lane = threadIdx.x & 63;
    const long long ch = (long long)blockIdx.x * 4 + wave;
    if (ch >= NCH) return;
    const float* base = x + ch * HW;

    float full = 0.f, ring = 0.f;
#pragma unroll
    for (int j = 0; j < 4; ++j) {
        int idx = lane + 64 * j;
        if (idx < HW) {
            float v = base[idx];
            full += v;
            int h = idx / 15, w = idx - h * 15;
            if (h >= 6 && h <= 8 && w >= 6 && w <= 8) ring += v;
        }
    }
#pragma unroll
    for (int off = 32; off > 0; off >>= 1) {
        full += __shfl_down(full, off, 64);
        ring += __shfl_down(ring, off, 64);
    }
    if (lane == 0) {
        M[ch] = full * (1.0f / 225.0f);
        R[ch] = ring * (1.0f / 225.0f);
    }
}

__device__ __forceinline__ float sigmoidf(float v) {
    return 1.0f / (1.0f + __expf(-v));
}

// Kernel 2: compute the per-channel gate (redundantly on all lanes — the
// 20 M/R loads are same-address broadcasts, L2-hot) and scale the 225 pixels.
__global__ __launch_bounds__(256) void scale_kernel(
    const float* __restrict__ x,
    const float* __restrict__ M, const float* __restrict__ R,
    const float* __restrict__ w1, const float* __restrict__ b1,
    const float* __restrict__ w2, const float* __restrict__ b2,
    float* __restrict__ out)
{
    const int wave = threadIdx.x >> 6;
    const int lane = threadIdx.x & 63;
    const long long ch = (long long)blockIdx.x * 4 + wave;
    if (ch >= NCH) return;
    const int b = (int)(ch / CC);
    const int c = (int)(ch - (long long)b * CC);

    const float* Mb = M + (long long)b * CC;
    const float* Rb = R + (long long)b * CC;

    // w shape (1,1,2,5): row0 = w[0..4] applies to forward means,
    // row1 = w[5..9] applies to the channel-reversed means.
    float g1 = b1[0], g2 = b2[0];
#pragma unroll
    for (int k = 0; k < 5; ++k) {
        int j = c + k - 2;
        if (j >= 0 && j < CC) {
            g1 += w1[k] * Mb[j] + w1[5 + k] * Mb[CC - 1 - j];
            g2 += w2[k] * Rb[j] + w2[5 + k] * Rb[CC - 1 - j];
        }
    }
    const float a1 = sigmoidf(g1);
    const float a2 = sigmoidf(g2);
    const float at = sigmoidf((a1 * a2 - 0.2f) * 2.0f);

    const float* bx = x + ch * HW;
    float* bo = out + ch * HW;
#pragma unroll
    for (int j = 0; j < 4; ++j) {
        int idx = lane + 64 * j;
        if (idx < HW) bo[idx] = bx[idx] * at;
    }
}

extern "C" void kernel_launch(void* const* d_in, const int* in_sizes, int n_in,
                              void* d_out, int out_size, void* d_ws, size_t ws_size,
                              hipStream_t stream)
{
    const float* x  = (const float*)d_in[0];
    const float* w1 = (const float*)d_in[1];
    const float* b1 = (const float*)d_in[2];
    const float* w2 = (const float*)d_in[3];
    const float* b2 = (const float*)d_in[4];
    float* out = (float*)d_out;

    float* M = (float*)d_ws;            // NCH floats
    float* R = M + NCH;                 // NCH floats

    const int blocks = NCH / 4;         // 4 waves (channels) per block
    means_kernel<<<blocks, 256, 0, stream>>>(x, M, R);
    scale_kernel<<<blocks, 256, 0, stream>>>(x, M, R, w1, b1, w2, b2, out);
}

// Round 2
// 403.379 us; speedup vs baseline: 1.2016x; 1.2016x over previous
//
#include <hip/hip_runtime.h>
#include <math.h>

// Problem constants (fixed by setup_inputs)
#define BB 512
#define CC 480            // C1*C2 = 16*30 channels per batch
#define HW 225            // 15*15 pixels per channel
#define CHW (CC * HW)     // 108000 floats per batch
#define NF4 (CHW / 4)     // 27000 float4 per batch
#define NGRP (CC / 4)     // 120 groups of 4 channels (900 floats = 225 f4, 16B-aligned)
#define NTHREADS 1024
#define NWAVES (NTHREADS / 64)

using f4 = __attribute__((ext_vector_type(4))) float;

__device__ __forceinline__ float sigmoidf(float v) {
    return 1.0f / (1.0f + __expf(-v));
}

// One block per batch. Phase 1: per-channel full & center-3x3 sums -> LDS.
// Phase 2: per-channel gate. Phase 3: streaming scale with f4 loads and
// nontemporal f4 stores (keep x resident in L3 for the re-read).
__global__ __launch_bounds__(NTHREADS) void fused_kernel(
    const float* __restrict__ x,
    const float* __restrict__ w1, const float* __restrict__ b1,
    const float* __restrict__ w2, const float* __restrict__ b2,
    float* __restrict__ out)
{
    __shared__ float Ms[CC];   // full means
    __shared__ float Rs[CC];   // ring (center 3x3) means
    __shared__ float As[CC];   // gate per channel

    const int b = blockIdx.x;
    const int t = threadIdx.x;
    const int wave = t >> 6;
    const int lane = t & 63;

    const f4* __restrict__ xb4 = (const f4*)(x + (long long)b * CHW);

    // ---------------- Phase 1: per-channel sums (4-channel groups) ----------
    for (int gr = wave; gr < NGRP; gr += NWAVES) {
        const f4* gp = xb4 + gr * 225;   // 4 channels = 225 float4
        float f0 = 0.f, f1 = 0.f, f2 = 0.f, f3 = 0.f;
        float r0 = 0.f, r1 = 0.f, r2 = 0.f, r3 = 0.f;
#pragma unroll
        for (int j = 0; j < 4; ++j) {
            const int idx = lane + 64 * j;
            if (idx < 225) {
                f4 v = gp[idx];
                const int e0 = 4 * idx;
#pragma unroll
                for (int jj = 0; jj < 4; ++jj) {
                    const int e = e0 + jj;                    // 0..899
                    const float vv = v[jj];
                    const int q = (e >= 450) ? ((e >= 675) ? 3 : 2)
                                             : ((e >= 225) ? 1 : 0);
                    const int r = e - 225 * q;                // 0..224
                    const bool ring = (r >= 96 && r <= 98) ||
                                      (r >= 111 && r <= 113) ||
                                      (r >= 126 && r <= 128);
                    const float rv = ring ? vv : 0.f;
                    f0 += (q == 0) ? vv : 0.f;
                    f1 += (q == 1) ? vv : 0.f;
                    f2 += (q == 2) ? vv : 0.f;
                    f3 += (q == 3) ? vv : 0.f;
                    r0 += (q == 0) ? rv : 0.f;
                    r1 += (q == 1) ? rv : 0.f;
                    r2 += (q == 2) ? rv : 0.f;
                    r3 += (q == 3) ? rv : 0.f;
                }
            }
        }
#pragma unroll
        for (int off = 32; off > 0; off >>= 1) {
            f0 += __shfl_down(f0, off, 64);
            f1 += __shfl_down(f1, off, 64);
            f2 += __shfl_down(f2, off, 64);
            f3 += __shfl_down(f3, off, 64);
            r0 += __shfl_down(r0, off, 64);
            r1 += __shfl_down(r1, off, 64);
            r2 += __shfl_down(r2, off, 64);
            r3 += __shfl_down(r3, off, 64);
        }
        if (lane == 0) {
            const float s = 1.0f / 225.0f;
            Ms[4 * gr + 0] = f0 * s;  Rs[4 * gr + 0] = r0 * s;
            Ms[4 * gr + 1] = f1 * s;  Rs[4 * gr + 1] = r1 * s;
            Ms[4 * gr + 2] = f2 * s;  Rs[4 * gr + 2] = r2 * s;
            Ms[4 * gr + 3] = f3 * s;  Rs[4 * gr + 3] = r3 * s;
        }
    }
    __syncthreads();

    // ---------------- Phase 2: per-channel gates ---------------------------
    if (t < CC) {
        const int c = t;
        float g1 = b1[0], g2 = b2[0];
#pragma unroll
        for (int k = 0; k < 5; ++k) {
            const int j = c + k - 2;
            if (j >= 0 && j < CC) {
                g1 += w1[k] * Ms[j] + w1[5 + k] * Ms[CC - 1 - j];
                g2 += w2[k] * Rs[j] + w2[5 + k] * Rs[CC - 1 - j];
            }
        }
        As[c] = sigmoidf((sigmoidf(g1) * sigmoidf(g2) - 0.2f) * 2.0f);
    }
    __syncthreads();

    // ---------------- Phase 3: streaming scale -----------------------------
    f4* __restrict__ ob4 = (f4*)(out + (long long)b * CHW);
    for (int g = t; g < NF4; g += NTHREADS) {
        f4 v = xb4[g];
        const int e0 = 4 * g;
        const int c0 = e0 / 225;            // compiler emits magic-mul
        const int rr = e0 - 225 * c0;
        const int c1 = c0 + (rr >= 224);
        const int c2 = c0 + (rr >= 223);
        const int c3 = c0 + (rr >= 222);
        v[0] *= As[c0];
        v[1] *= As[c1];
        v[2] *= As[c2];
        v[3] *= As[c3];
        __builtin_nontemporal_store(v, &ob4[g]);
    }
}

extern "C" void kernel_launch(void* const* d_in, const int* in_sizes, int n_in,
                              void* d_out, int out_size, void* d_ws, size_t ws_size,
                              hipStream_t stream)
{
    const float* x  = (const float*)d_in[0];
    const float* w1 = (const float*)d_in[1];
    const float* b1 = (const float*)d_in[2];
    const float* w2 = (const float*)d_in[3];
    const float* b2 = (const float*)d_in[4];
    float* out = (float*)d_out;

    fused_kernel<<<BB, NTHREADS, 0, stream>>>(x, w1, b1, w2, b2, out);
}